// Round 1
// baseline (580.667 us; speedup 1.0000x reference)
//
#include <hip/hip_runtime.h>

// DCNv2 forward: B=4, Cin=64, Cout=64, K=3, H=W=128, S=1, P=1
constexpr int B    = 4;
constexpr int Cin  = 64;
constexpr int Cout = 64;
constexpr int K    = 3;
constexpr int H    = 128;
constexpr int W    = 128;
constexpr int KK   = K * K;          // 9
constexpr int HW   = H * W;          // 16384
constexpr int OFF_C = 2 * KK;        // 18 offset channels (mask is unused by reference!)
constexpr int OFFSET_ELEMS = B * OFF_C * HW;   // 1,179,648
constexpr int CK = Cin * KK;         // 576
constexpr int PIX = 16;              // pixels per block
constexpr int SAMP_STRIDE = CK + 4;  // 580: multiple of 4 (b128 align), %32==4 (bank spread)

// ---------------- Kernel A: 3x3 conv producing the 18 offset channels ----------------
__global__ __launch_bounds__(256)
void offset_conv(const float* __restrict__ oin,   // (B,Cin,H,W)
                 const float* __restrict__ cmw,   // (27,Cin,3,3)
                 const float* __restrict__ cmb,   // (27,)
                 float* __restrict__ offs)        // (B,18,H,W)
{
    int t = blockIdx.x * 256 + threadIdx.x;       // exact: B*18*HW threads
    int w  = t & (W - 1);
    int h  = (t >> 7) & (H - 1);
    int oc = (t >> 14) % OFF_C;
    int b  = (t >> 14) / OFF_C;

    float acc = cmb[oc];
    const float* wrow  = cmw + oc * Cin * KK;
    const float* ibase = oin + b * Cin * HW;

    for (int c = 0; c < Cin; ++c) {
        const float* ip = ibase + c * HW;
        const float* wp = wrow + c * KK;
        #pragma unroll
        for (int ky = 0; ky < 3; ++ky) {
            int yy = h + ky - 1;
            if ((unsigned)yy >= (unsigned)H) continue;
            #pragma unroll
            for (int kx = 0; kx < 3; ++kx) {
                int xx = w + kx - 1;
                if ((unsigned)xx >= (unsigned)W) continue;
                acc = fmaf(ip[yy * W + xx], wp[ky * 3 + kx], acc);
            }
        }
    }
    offs[t] = acc;
}

// ---------------- Kernel B: bilinear deform sample + per-pixel 64x576 matvec ----------------
__global__ __launch_bounds__(256)
void deform_gemm(const float* __restrict__ x,     // (B,Cin,H,W)
                 const float* __restrict__ offs,  // (B,18,H,W)
                 const float* __restrict__ wgt,   // (Cout, CK)
                 const float* __restrict__ bias,  // (Cout,)
                 float* __restrict__ y)           // (B,Cout,H,W)
{
    __shared__ float samp[PIX][SAMP_STRIDE];      // 16*580*4 = 37,120 B
    __shared__ int   s_iy[KK * PIX];
    __shared__ int   s_ix[KK * PIX];
    __shared__ float s_wy[KK * PIX];
    __shared__ float s_wx[KK * PIX];

    int blk    = blockIdx.x;          // B*H*(W/16) = 4096
    int wchunk = blk & (W / PIX - 1); // 0..7
    int h      = (blk >> 3) & (H - 1);
    int b      = blk >> 10;
    int w0     = wchunk * PIX;
    int tid    = threadIdx.x;

    // ---- phase 1: bilinear metadata for 9 taps x 16 pixels ----
    if (tid < KK * PIX) {
        int p = tid & (PIX - 1);
        int k = tid >> 4;
        int w = w0 + p;
        float dyv = offs[((b * OFF_C + 2 * k    ) * H + h) * W + w];
        float dxv = offs[((b * OFF_C + 2 * k + 1) * H + h) * W + w];
        float py = dyv + (float)(h - 1 + k / 3);
        float px = dxv + (float)(w - 1 + k % 3);
        float fy = floorf(py), fx = floorf(px);
        s_iy[tid] = (int)fy;
        s_ix[tid] = (int)fx;
        s_wy[tid] = py - fy;
        s_wx[tid] = px - fx;
    }
    __syncthreads();

    // ---- phase 2: sample all (c,k,p) into LDS, layout [p][c*9+k] ----
    const float* xb = x + b * Cin * HW;
    for (int i = tid; i < Cin * KK * PIX; i += 256) {
        int p = i & (PIX - 1);
        int k = (i >> 4) % KK;
        int c = i / (KK * PIX);
        int m = k * PIX + p;
        int iy = s_iy[m], ix = s_ix[m];
        float wy = s_wy[m], wx = s_wx[m];
        const float* xp = xb + c * HW;
        float v00 = 0.f, v01 = 0.f, v10 = 0.f, v11 = 0.f;
        bool y0ok = (unsigned)iy       < (unsigned)H;
        bool y1ok = (unsigned)(iy + 1) < (unsigned)H;
        bool x0ok = (unsigned)ix       < (unsigned)W;
        bool x1ok = (unsigned)(ix + 1) < (unsigned)W;
        if (y0ok && x0ok) v00 = xp[iy * W + ix];
        if (y0ok && x1ok) v01 = xp[iy * W + ix + 1];
        if (y1ok && x0ok) v10 = xp[(iy + 1) * W + ix];
        if (y1ok && x1ok) v11 = xp[(iy + 1) * W + ix + 1];
        float v = (v00 * (1.f - wx) + v01 * wx) * (1.f - wy)
                + (v10 * (1.f - wx) + v11 * wx) * wy;
        samp[p][c * KK + k] = v;
    }
    __syncthreads();

    // ---- phase 3: out[o][p] = sum_ck W[o][ck] * samp[p][ck] ----
    int tp = tid & (PIX - 1);   // pixel
    int to = tid >> 4;          // 0..15 -> o = og*16 + to
    float acc0 = 0.f, acc1 = 0.f, acc2 = 0.f, acc3 = 0.f;

    for (int ck = 0; ck < CK; ck += 4) {
        float4 sv = *reinterpret_cast<const float4*>(&samp[tp][ck]);
        const float4 w0v = *reinterpret_cast<const float4*>(&wgt[(0 * 16 + to) * CK + ck]);
        const float4 w1v = *reinterpret_cast<const float4*>(&wgt[(1 * 16 + to) * CK + ck]);
        const float4 w2v = *reinterpret_cast<const float4*>(&wgt[(2 * 16 + to) * CK + ck]);
        const float4 w3v = *reinterpret_cast<const float4*>(&wgt[(3 * 16 + to) * CK + ck]);
        acc0 = fmaf(sv.x, w0v.x, acc0); acc0 = fmaf(sv.y, w0v.y, acc0);
        acc0 = fmaf(sv.z, w0v.z, acc0); acc0 = fmaf(sv.w, w0v.w, acc0);
        acc1 = fmaf(sv.x, w1v.x, acc1); acc1 = fmaf(sv.y, w1v.y, acc1);
        acc1 = fmaf(sv.z, w1v.z, acc1); acc1 = fmaf(sv.w, w1v.w, acc1);
        acc2 = fmaf(sv.x, w2v.x, acc2); acc2 = fmaf(sv.y, w2v.y, acc2);
        acc2 = fmaf(sv.z, w2v.z, acc2); acc2 = fmaf(sv.w, w2v.w, acc2);
        acc3 = fmaf(sv.x, w3v.x, acc3); acc3 = fmaf(sv.y, w3v.y, acc3);
        acc3 = fmaf(sv.z, w3v.z, acc3); acc3 = fmaf(sv.w, w3v.w, acc3);
    }

    int wcol = w0 + tp;
    {
        int o = 0 * 16 + to;
        y[((b * Cout + o) * H + h) * W + wcol] = acc0 + bias[o];
    }
    {
        int o = 1 * 16 + to;
        y[((b * Cout + o) * H + h) * W + wcol] = acc1 + bias[o];
    }
    {
        int o = 2 * 16 + to;
        y[((b * Cout + o) * H + h) * W + wcol] = acc2 + bias[o];
    }
    {
        int o = 3 * 16 + to;
        y[((b * Cout + o) * H + h) * W + wcol] = acc3 + bias[o];
    }
}

extern "C" void kernel_launch(void* const* d_in, const int* in_sizes, int n_in,
                              void* d_out, int out_size, void* d_ws, size_t ws_size,
                              hipStream_t stream) {
    const float* x         = (const float*)d_in[0];
    const float* offset_in = (const float*)d_in[1];
    const float* weight    = (const float*)d_in[2];
    const float* bias      = (const float*)d_in[3];
    const float* cm_w      = (const float*)d_in[4];
    const float* cm_b      = (const float*)d_in[5];

    float* out  = (float*)d_out;
    float* offs = out;                    // output 0: (B,18,H,W)
    float* yout = out + OFFSET_ELEMS;     // output 1: (B,Cout,H,W)

    offset_conv<<<OFFSET_ELEMS / 256, 256, 0, stream>>>(offset_in, cm_w, cm_b, offs);
    deform_gemm<<<B * H * (W / PIX), 256, 0, stream>>>(x, offs, weight, bias, yout);
}

// Round 2
// 97.944 us; speedup vs baseline: 5.9286x; 5.9286x over previous
//
#include <hip/hip_runtime.h>
#include <hip/hip_bf16.h>

// DCNv2 forward: B=4, Cin=64, Cout=64, K=3, H=W=128, S=1, P=1
constexpr int B    = 4;
constexpr int Cin  = 64;
constexpr int Cout = 64;
constexpr int H    = 128;
constexpr int W    = 128;
constexpr int KK   = 9;
constexpr int HW   = H * W;
constexpr int OFF_C = 18;                       // mask channels unused by reference
constexpr int OFFSET_ELEMS = B * OFF_C * HW;
constexpr int CK   = Cin * KK;                  // 576
constexpr int SAMP_STRIDE = CK + 8;             // 584 ushorts = 1168B: 16B-aligned, %128B=16 -> 2-way banks

typedef __attribute__((ext_vector_type(8))) short  short8;
typedef __attribute__((ext_vector_type(4))) float  f32x4;

// ---- workspace layout (bf16 NHWC tensors + reordered bf16 weights) ----
constexpr size_t XT_OFF  = 0;                               // x_t[B][H][W][64] bf16
constexpr size_t XT_SZ   = (size_t)B * HW * 64 * 2;         // 8 MB
constexpr size_t OT_OFF  = XT_OFF + XT_SZ;                  // o_t (offset_in NHWC bf16)
constexpr size_t OT_SZ   = XT_SZ;
constexpr size_t WB_OFF  = OT_OFF + OT_SZ;                  // wb16[64][576], ck' = k*64+c
constexpr size_t WB_SZ   = (size_t)64 * CK * 2;
constexpr size_t CMB_OFF = WB_OFF + WB_SZ;                  // cmb16[32][576], rows>=18 zero
constexpr size_t CMB_SZ  = (size_t)32 * CK * 2;
constexpr size_t WS_NEEDED = CMB_OFF + CMB_SZ;              // ~16.9 MB

__device__ __forceinline__ unsigned short f2bf(float f) {   // round-to-nearest-even
    unsigned u = __builtin_bit_cast(unsigned, f);
    u += 0x7FFFu + ((u >> 16) & 1u);
    return (unsigned short)(u >> 16);
}
__device__ __forceinline__ float bf2f(unsigned short h) {
    unsigned u = (unsigned)h << 16;
    return __builtin_bit_cast(float, u);
}

// ================= prep 1: NCHW fp32 -> NHWC bf16 (x and offset_in) =================
__global__ __launch_bounds__(256)
void transpose_pack(const float* __restrict__ x, const float* __restrict__ oin,
                    unsigned short* __restrict__ x_t, unsigned short* __restrict__ o_t)
{
    __shared__ float tile[64][68];   // [w][c], stride 68 floats (bank-friendly, 16B-aligned)
    int idx = blockIdx.x;            // 2048: bit10 = tensor, bits 8-9 = b, 1-7 = h, 0 = wtile
    int tensor = idx >> 10;
    int blk = idx & 1023;
    int wt = blk & 1, h = (blk >> 1) & (H - 1), b = blk >> 8;
    const float* src = (tensor ? oin : x) + (size_t)b * Cin * HW + h * W + wt * 64;
    unsigned short* dst = (tensor ? o_t : x_t) + ((size_t)(b * H + h) * W + wt * 64) * 64;
    int t = threadIdx.x;
    int lane16 = t & 15, grp = t >> 4;

    #pragma unroll
    for (int i = 0; i < 4; ++i) {                 // coalesced 256B reads per 16-lane group
        int c = grp + 16 * i;
        float4 v = *reinterpret_cast<const float4*>(&src[c * HW + lane16 * 4]);
        int w0 = lane16 * 4;
        tile[w0 + 0][c] = v.x; tile[w0 + 1][c] = v.y;
        tile[w0 + 2][c] = v.z; tile[w0 + 3][c] = v.w;
    }
    __syncthreads();
    #pragma unroll
    for (int i = 0; i < 4; ++i) {                 // coalesced 128B bf16 writes
        int w = grp + 16 * i;
        const float* tr = &tile[w][lane16 * 4];
        ushort4 o4;
        o4.x = f2bf(tr[0]); o4.y = f2bf(tr[1]); o4.z = f2bf(tr[2]); o4.w = f2bf(tr[3]);
        *reinterpret_cast<ushort4*>(&dst[(size_t)w * 64 + lane16 * 4]) = o4;
    }
}

// ================= prep 2: weights -> bf16, reduction dim reordered ck' = k*64+c =================
__global__ __launch_bounds__(256)
void prep_weights(const float* __restrict__ wgt,   // (64, 64, 3, 3) = (64, c*9+k)
                  const float* __restrict__ cmw,   // (27, 64, 3, 3)
                  unsigned short* __restrict__ wb16,   // [64][576]
                  unsigned short* __restrict__ cmb16)  // [32][576], rows 18..31 zero
{
    int t = blockIdx.x * 256 + threadIdx.x;
    int stride = gridDim.x * 256;
    for (int i = t; i < 64 * CK; i += stride) {
        int o = i / CK, ckp = i - o * CK;
        int k = ckp >> 6, c = ckp & 63;
        wb16[i] = f2bf(wgt[(o * 64 + c) * 9 + k]);
    }
    for (int i = t; i < 32 * CK; i += stride) {
        int o = i / CK, ckp = i - o * CK;
        int k = ckp >> 6, c = ckp & 63;
        cmb16[i] = (o < OFF_C) ? f2bf(cmw[(o * 64 + c) * 9 + k]) : (unsigned short)0;
    }
}

// ================= kernel A: offset conv via im2col + MFMA =================
// C[32][32pix] = cmb16[32][576] x patch[576][32], only rows<18 stored.
__global__ __launch_bounds__(256)
void offset_conv_mfma(const unsigned short* __restrict__ o_t,
                      const unsigned short* __restrict__ cmb16,
                      const float* __restrict__ cmb,     // (27,)
                      float* __restrict__ offs)          // (B,18,H,W)
{
    __shared__ unsigned short patch[32][SAMP_STRIDE];    // 37,376 B
    int blk = blockIdx.x;               // B*H*4 = 2048
    int wc = blk & 3, h = (blk >> 2) & (H - 1), b = blk >> 9;
    int w0 = wc * 32;
    int tid = threadIdx.x;

    // im2col: 9k x 32p tasks, 16 threads each (4 c's per thread)
    for (int s = tid; s < 288 * 16; s += 256) {
        int sub = s & 15, task = s >> 4;
        int p = task & 31, k = task >> 5;
        int ky = k / 3, kx = k - ky * 3;
        int yy = h + ky - 1;
        int xx = w0 + p + kx - 1;
        ushort4 v = make_ushort4(0, 0, 0, 0);
        if ((unsigned)yy < (unsigned)H && (unsigned)xx < (unsigned)W)
            v = *reinterpret_cast<const ushort4*>(&o_t[((size_t)(b * H + yy) * W + xx) * 64 + sub * 4]);
        *reinterpret_cast<ushort4*>(&patch[p][k * 64 + sub * 4]) = v;
    }
    __syncthreads();

    int wv = tid >> 6, lane = tid & 63;
    int mtile = wv >> 1, ptile = wv & 1;
    int l16 = lane & 15, q = lane >> 4;
    f32x4 acc = {0.f, 0.f, 0.f, 0.f};
    const unsigned short* arow = cmb16 + (size_t)(mtile * 16 + l16) * CK;
    const unsigned short* brow = &patch[ptile * 16 + l16][0];
    #pragma unroll 6
    for (int ks = 0; ks < 18; ++ks) {
        short8 a  = *reinterpret_cast<const short8*>(&arow[ks * 32 + q * 8]);
        short8 bb = *reinterpret_cast<const short8*>(&brow[ks * 32 + q * 8]);
        acc = __builtin_amdgcn_mfma_f32_16x16x32_bf16(a, bb, acc, 0, 0, 0);
    }
    #pragma unroll
    for (int r = 0; r < 4; ++r) {                   // D: col=lane&15, row=(lane>>4)*4+r
        int o = mtile * 16 + q * 4 + r;
        if (o < OFF_C)
            offs[((size_t)(b * OFF_C + o) * H + h) * W + w0 + ptile * 16 + l16] = acc[r] + cmb[o];
    }
}

// ================= kernel B: deform sample + MFMA GEMM =================
// per block: 16 pixels; C[64][16] = wb16[64][576] x samp[576][16]
__global__ __launch_bounds__(256)
void deform_mfma(const unsigned short* __restrict__ x_t,
                 const float* __restrict__ offs,
                 const unsigned short* __restrict__ wb16,
                 const float* __restrict__ bias,
                 float* __restrict__ y)
{
    __shared__ unsigned short samp[16][SAMP_STRIDE];     // 18,688 B
    __shared__ int   s_a00[144], s_a01[144], s_a10[144], s_a11[144];
    __shared__ float s_w00[144], s_w01[144], s_w10[144], s_w11[144];

    int blk = blockIdx.x;              // B*H*8 = 4096
    int wc = blk & 7, h = (blk >> 3) & (H - 1), b = blk >> 10;
    int w0 = wc * 16;
    int tid = threadIdx.x;

    // phase 1: bilinear meta for 9 taps x 16 pixels
    if (tid < 144) {
        int p = tid & 15, k = tid >> 4;
        int ky = k / 3, kx = k - ky * 3;
        int w = w0 + p;
        float dyv = offs[((size_t)(b * OFF_C + 2 * k    ) * H + h) * W + w];
        float dxv = offs[((size_t)(b * OFF_C + 2 * k + 1) * H + h) * W + w];
        float py = dyv + (float)(h - 1 + ky);
        float px = dxv + (float)(w - 1 + kx);
        float fy = floorf(py), fx = floorf(px);
        int iy = (int)fy, ix = (int)fx;
        float wy = py - fy, wx = px - fx;
        bool y0 = (unsigned)iy       < (unsigned)H;
        bool y1 = (unsigned)(iy + 1) < (unsigned)H;
        bool x0 = (unsigned)ix       < (unsigned)W;
        bool x1 = (unsigned)(ix + 1) < (unsigned)W;
        int cy0 = min(max(iy, 0), H - 1),     cy1 = min(max(iy + 1, 0), H - 1);
        int cx0 = min(max(ix, 0), W - 1),     cx1 = min(max(ix + 1, 0), W - 1);
        int rb = b * H;
        s_a00[tid] = ((rb + cy0) * W + cx0) * 64;
        s_a01[tid] = ((rb + cy0) * W + cx1) * 64;
        s_a10[tid] = ((rb + cy1) * W + cx0) * 64;
        s_a11[tid] = ((rb + cy1) * W + cx1) * 64;
        s_w00[tid] = (y0 && x0) ? (1.f - wy) * (1.f - wx) : 0.f;
        s_w01[tid] = (y0 && x1) ? (1.f - wy) * wx         : 0.f;
        s_w10[tid] = (y1 && x0) ? wy * (1.f - wx)         : 0.f;
        s_w11[tid] = (y1 && x1) ? wy * wx                 : 0.f;
    }
    __syncthreads();

    // phase 2: 144 tasks x 16 threads; contiguous-c corner loads, blend, bf16 pack
    for (int s = tid; s < 144 * 16; s += 256) {
        int sub = s & 15, task = s >> 4;
        int p = task & 15, k = task >> 4;
        int c0 = sub * 4;
        int a00 = s_a00[task], a01 = s_a01[task], a10 = s_a10[task], a11 = s_a11[task];
        float w00 = s_w00[task], w01 = s_w01[task], w10 = s_w10[task], w11 = s_w11[task];
        ushort4 v00 = *reinterpret_cast<const ushort4*>(&x_t[a00 + c0]);
        ushort4 v01 = *reinterpret_cast<const ushort4*>(&x_t[a01 + c0]);
        ushort4 v10 = *reinterpret_cast<const ushort4*>(&x_t[a10 + c0]);
        ushort4 v11 = *reinterpret_cast<const ushort4*>(&x_t[a11 + c0]);
        ushort4 o4;
        o4.x = f2bf(w00 * bf2f(v00.x) + w01 * bf2f(v01.x) + w10 * bf2f(v10.x) + w11 * bf2f(v11.x));
        o4.y = f2bf(w00 * bf2f(v00.y) + w01 * bf2f(v01.y) + w10 * bf2f(v10.y) + w11 * bf2f(v11.y));
        o4.z = f2bf(w00 * bf2f(v00.z) + w01 * bf2f(v01.z) + w10 * bf2f(v10.z) + w11 * bf2f(v11.z));
        o4.w = f2bf(w00 * bf2f(v00.w) + w01 * bf2f(v01.w) + w10 * bf2f(v10.w) + w11 * bf2f(v11.w));
        *reinterpret_cast<ushort4*>(&samp[p][k * 64 + c0]) = o4;
    }
    __syncthreads();

    // phase 3: wave wv computes out-channels [wv*16, wv*16+16) x 16 pixels
    int wv = tid >> 6, lane = tid & 63;
    int l16 = lane & 15, q = lane >> 4;
    f32x4 acc = {0.f, 0.f, 0.f, 0.f};
    const unsigned short* arow = wb16 + (size_t)(wv * 16 + l16) * CK;
    const unsigned short* brow = &samp[l16][0];
    #pragma unroll 6
    for (int ks = 0; ks < 18; ++ks) {
        short8 a  = *reinterpret_cast<const short8*>(&arow[ks * 32 + q * 8]);
        short8 bb = *reinterpret_cast<const short8*>(&brow[ks * 32 + q * 8]);
        acc = __builtin_amdgcn_mfma_f32_16x16x32_bf16(a, bb, acc, 0, 0, 0);
    }
    #pragma unroll
    for (int r = 0; r < 4; ++r) {
        int o = wv * 16 + q * 4 + r;
        y[((size_t)(b * Cout + o) * H + h) * W + w0 + l16] = acc[r] + bias[o];
    }
}

// ======================= fallback fp32 path (round-1 kernels) =======================
__global__ __launch_bounds__(256)
void offset_conv_fb(const float* __restrict__ oin, const float* __restrict__ cmw,
                    const float* __restrict__ cmb, float* __restrict__ offs)
{
    int t = blockIdx.x * 256 + threadIdx.x;
    int w = t & (W - 1);
    int h = (t >> 7) & (H - 1);
    int oc = (t >> 14) % OFF_C;
    int b  = (t >> 14) / OFF_C;
    float acc = cmb[oc];
    const float* wrow  = cmw + oc * Cin * KK;
    const float* ibase = oin + b * Cin * HW;
    for (int c = 0; c < Cin; ++c) {
        const float* ip = ibase + c * HW;
        const float* wp = wrow + c * KK;
        #pragma unroll
        for (int ky = 0; ky < 3; ++ky) {
            int yy = h + ky - 1;
            if ((unsigned)yy >= (unsigned)H) continue;
            #pragma unroll
            for (int kx = 0; kx < 3; ++kx) {
                int xx = w + kx - 1;
                if ((unsigned)xx >= (unsigned)W) continue;
                acc = fmaf(ip[yy * W + xx], wp[ky * 3 + kx], acc);
            }
        }
    }
    offs[t] = acc;
}

__global__ __launch_bounds__(256)
void deform_gemm_fb(const float* __restrict__ x, const float* __restrict__ offs,
                    const float* __restrict__ wgt, const float* __restrict__ bias,
                    float* __restrict__ y)
{
    __shared__ float samp[16][580];
    __shared__ int   s_iy[144];
    __shared__ int   s_ix[144];
    __shared__ float s_wy[144];
    __shared__ float s_wx[144];
    int blk = blockIdx.x;
    int wchunk = blk & 7;
    int h = (blk >> 3) & (H - 1);
    int b = blk >> 10;
    int w0 = wchunk * 16;
    int tid = threadIdx.x;
    if (tid < 144) {
        int p = tid & 15, k = tid >> 4;
        int w = w0 + p;
        float dyv = offs[((b * OFF_C + 2 * k    ) * H + h) * W + w];
        float dxv = offs[((b * OFF_C + 2 * k + 1) * H + h) * W + w];
        float py = dyv + (float)(h - 1 + k / 3);
        float px = dxv + (float)(w - 1 + k % 3);
        float fy = floorf(py), fx = floorf(px);
        s_iy[tid] = (int)fy; s_ix[tid] = (int)fx;
        s_wy[tid] = py - fy; s_wx[tid] = px - fx;
    }
    __syncthreads();
    const float* xb = x + b * Cin * HW;
    for (int i = tid; i < Cin * KK * 16; i += 256) {
        int p = i & 15;
        int k = (i >> 4) % KK;
        int c = i / (KK * 16);
        int m = k * 16 + p;
        int iy = s_iy[m], ix = s_ix[m];
        float wy = s_wy[m], wx = s_wx[m];
        const float* xp = xb + c * HW;
        float v00 = 0.f, v01 = 0.f, v10 = 0.f, v11 = 0.f;
        bool y0ok = (unsigned)iy       < (unsigned)H;
        bool y1ok = (unsigned)(iy + 1) < (unsigned)H;
        bool x0ok = (unsigned)ix       < (unsigned)W;
        bool x1ok = (unsigned)(ix + 1) < (unsigned)W;
        if (y0ok && x0ok) v00 = xp[iy * W + ix];
        if (y0ok && x1ok) v01 = xp[iy * W + ix + 1];
        if (y1ok && x0ok) v10 = xp[(iy + 1) * W + ix];
        if (y1ok && x1ok) v11 = xp[(iy + 1) * W + ix + 1];
        samp[p][c * KK + k] = (v00 * (1.f - wx) + v01 * wx) * (1.f - wy)
                            + (v10 * (1.f - wx) + v11 * wx) * wy;
    }
    __syncthreads();
    int tp = tid & 15, to = tid >> 4;
    float acc0 = 0.f, acc1 = 0.f, acc2 = 0.f, acc3 = 0.f;
    for (int ck = 0; ck < CK; ck += 4) {
        float4 sv = *reinterpret_cast<const float4*>(&samp[tp][ck]);
        const float4 w0v = *reinterpret_cast<const float4*>(&wgt[(0 * 16 + to) * CK + ck]);
        const float4 w1v = *reinterpret_cast<const float4*>(&wgt[(1 * 16 + to) * CK + ck]);
        const float4 w2v = *reinterpret_cast<const float4*>(&wgt[(2 * 16 + to) * CK + ck]);
        const float4 w3v = *reinterpret_cast<const float4*>(&wgt[(3 * 16 + to) * CK + ck]);
        acc0 = fmaf(sv.x, w0v.x, acc0); acc0 = fmaf(sv.y, w0v.y, acc0);
        acc0 = fmaf(sv.z, w0v.z, acc0); acc0 = fmaf(sv.w, w0v.w, acc0);
        acc1 = fmaf(sv.x, w1v.x, acc1); acc1 = fmaf(sv.y, w1v.y, acc1);
        acc1 = fmaf(sv.z, w1v.z, acc1); acc1 = fmaf(sv.w, w1v.w, acc1);
        acc2 = fmaf(sv.x, w2v.x, acc2); acc2 = fmaf(sv.y, w2v.y, acc2);
        acc2 = fmaf(sv.z, w2v.z, acc2); acc2 = fmaf(sv.w, w2v.w, acc2);
        acc3 = fmaf(sv.x, w3v.x, acc3); acc3 = fmaf(sv.y, w3v.y, acc3);
        acc3 = fmaf(sv.z, w3v.z, acc3); acc3 = fmaf(sv.w, w3v.w, acc3);
    }
    int wcol = w0 + tp;
    y[((b * Cout + (0 * 16 + to)) * H + h) * W + wcol] = acc0 + bias[0 * 16 + to];
    y[((b * Cout + (1 * 16 + to)) * H + h) * W + wcol] = acc1 + bias[1 * 16 + to];
    y[((b * Cout + (2 * 16 + to)) * H + h) * W + wcol] = acc2 + bias[2 * 16 + to];
    y[((b * Cout + (3 * 16 + to)) * H + h) * W + wcol] = acc3 + bias[3 * 16 + to];
}

extern "C" void kernel_launch(void* const* d_in, const int* in_sizes, int n_in,
                              void* d_out, int out_size, void* d_ws, size_t ws_size,
                              hipStream_t stream) {
    const float* x         = (const float*)d_in[0];
    const float* offset_in = (const float*)d_in[1];
    const float* weight    = (const float*)d_in[2];
    const float* bias      = (const float*)d_in[3];
    const float* cm_w      = (const float*)d_in[4];
    const float* cm_b      = (const float*)d_in[5];

    float* out  = (float*)d_out;
    float* offs = out;                    // output 0: (B,18,H,W)
    float* yout = out + OFFSET_ELEMS;     // output 1: (B,64,H,W)

    if (ws_size >= WS_NEEDED) {
        unsigned short* x_t   = (unsigned short*)((char*)d_ws + XT_OFF);
        unsigned short* o_t   = (unsigned short*)((char*)d_ws + OT_OFF);
        unsigned short* wb16  = (unsigned short*)((char*)d_ws + WB_OFF);
        unsigned short* cmb16 = (unsigned short*)((char*)d_ws + CMB_OFF);

        transpose_pack<<<2048, 256, 0, stream>>>(x, offset_in, x_t, o_t);
        prep_weights<<<64, 256, 0, stream>>>(weight, cm_w, wb16, cmb16);
        offset_conv_mfma<<<B * H * (W / 32), 256, 0, stream>>>(o_t, cmb16, cm_b, offs);
        deform_mfma<<<B * H * (W / 16), 256, 0, stream>>>(x_t, offs, wb16, bias, yout);
    } else {
        offset_conv_fb<<<OFFSET_ELEMS / 256, 256, 0, stream>>>(offset_in, cm_w, cm_b, offs);
        deform_gemm_fb<<<B * H * (W / 16), 256, 0, stream>>>(x, offs, weight, bias, yout);
    }
}

// Round 3
// 89.026 us; speedup vs baseline: 6.5224x; 1.1002x over previous
//
#include <hip/hip_runtime.h>

// DCNv2 forward: B=4, Cin=64, Cout=64, K=3, H=W=128, S=1, P=1
constexpr int B    = 4;
constexpr int Cin  = 64;
constexpr int Cout = 64;
constexpr int H    = 128;
constexpr int W    = 128;
constexpr int KK   = 9;
constexpr int HW   = H * W;
constexpr int OFF_C = 18;                       // mask channels unused by reference
constexpr int OFFSET_ELEMS = B * OFF_C * HW;
constexpr int CK   = Cin * KK;                  // 576
constexpr int SAMP_STRIDE = CK + 8;             // 584 ushorts = 1168B (16B-aligned)
constexpr int PIX  = 32;                        // pixels per fused block
constexpr int NT   = KK * PIX;                  // 288 (k,p) tasks per block

typedef __attribute__((ext_vector_type(8))) short  short8;
typedef __attribute__((ext_vector_type(4))) float  f32x4;

// ---- workspace layout (bf16 NHWC tensors + reordered bf16 weights) ----
constexpr size_t XT_OFF  = 0;                               // x_t[B][H][W][64] bf16
constexpr size_t XT_SZ   = (size_t)B * HW * 64 * 2;
constexpr size_t OT_OFF  = XT_OFF + XT_SZ;                  // o_t NHWC bf16
constexpr size_t OT_SZ   = XT_SZ;
constexpr size_t WB_OFF  = OT_OFF + OT_SZ;                  // wb16[64][576], ck' = k*64+c
constexpr size_t WB_SZ   = (size_t)64 * CK * 2;
constexpr size_t CMB_OFF = WB_OFF + WB_SZ;                  // cmb16[32][576], rows>=18 zero
constexpr size_t CMB_SZ  = (size_t)32 * CK * 2;
constexpr size_t WS_NEEDED = CMB_OFF + CMB_SZ;

__device__ __forceinline__ unsigned short f2bf(float f) {   // round-to-nearest-even
    unsigned u = __builtin_bit_cast(unsigned, f);
    u += 0x7FFFu + ((u >> 16) & 1u);
    return (unsigned short)(u >> 16);
}
__device__ __forceinline__ float bf2f(unsigned short h) {
    unsigned u = (unsigned)h << 16;
    return __builtin_bit_cast(float, u);
}

// ============ prep: NCHW fp32 -> NHWC bf16 (x, offset_in) + weight reorder ============
__global__ __launch_bounds__(256)
void prep_all(const float* __restrict__ x, const float* __restrict__ oin,
              const float* __restrict__ wgt, const float* __restrict__ cmw,
              unsigned short* __restrict__ x_t, unsigned short* __restrict__ o_t,
              unsigned short* __restrict__ wb16, unsigned short* __restrict__ cmb16)
{
    __shared__ float tile[64][68];
    int idx = blockIdx.x;
    int t = threadIdx.x;
    if (idx < 2048) {                 // transpose: bit10 = tensor, bits 8-9 = b, 1-7 = h, 0 = wtile
        int tensor = idx >> 10;
        int blk = idx & 1023;
        int wt = blk & 1, h = (blk >> 1) & (H - 1), b = blk >> 8;
        const float* src = (tensor ? oin : x) + (size_t)b * Cin * HW + h * W + wt * 64;
        unsigned short* dst = (tensor ? o_t : x_t) + ((size_t)(b * H + h) * W + wt * 64) * 64;
        int lane16 = t & 15, grp = t >> 4;
        #pragma unroll
        for (int i = 0; i < 4; ++i) {
            int c = grp + 16 * i;
            float4 v = *reinterpret_cast<const float4*>(&src[c * HW + lane16 * 4]);
            int w0 = lane16 * 4;
            tile[w0 + 0][c] = v.x; tile[w0 + 1][c] = v.y;
            tile[w0 + 2][c] = v.z; tile[w0 + 3][c] = v.w;
        }
        __syncthreads();
        #pragma unroll
        for (int i = 0; i < 4; ++i) {
            int w = grp + 16 * i;
            const float* tr = &tile[w][lane16 * 4];
            ushort4 o4;
            o4.x = f2bf(tr[0]); o4.y = f2bf(tr[1]); o4.z = f2bf(tr[2]); o4.w = f2bf(tr[3]);
            *reinterpret_cast<ushort4*>(&dst[(size_t)w * 64 + lane16 * 4]) = o4;
        }
    } else {                          // weight prep: 64 blocks
        int i0 = (idx - 2048) * 256 + t;
        int stride = 64 * 256;
        for (int i = i0; i < 64 * CK; i += stride) {
            int o = i / CK, ckp = i - o * CK;
            int k = ckp >> 6, c = ckp & 63;
            wb16[i] = f2bf(wgt[(o * 64 + c) * 9 + k]);
        }
        for (int i = i0; i < 32 * CK; i += stride) {
            int o = i / CK, ckp = i - o * CK;
            int k = ckp >> 6, c = ckp & 63;
            cmb16[i] = (o < OFF_C) ? f2bf(cmw[(o * 64 + c) * 9 + k]) : (unsigned short)0;
        }
    }
}

// ============ fused: offset-conv MFMA -> bilinear sample -> main MFMA ============
__global__ __launch_bounds__(512, 6)
void dcn_fused(const unsigned short* __restrict__ x_t,
               const unsigned short* __restrict__ o_t,
               const unsigned short* __restrict__ wb16,
               const unsigned short* __restrict__ cmb16,
               const float* __restrict__ cmb,     // (27,)
               const float* __restrict__ bias,    // (64,)
               float* __restrict__ offs_out,      // (B,18,H,W)
               float* __restrict__ y_out)         // (B,64,H,W)
{
    __shared__ unsigned short stage[PIX][SAMP_STRIDE];   // 37,376 B: o_t patch, then samp
    __shared__ float offs_l[OFF_C][PIX];                 // 2,304 B
    __shared__ int   s_a00[NT], s_a01[NT], s_a10[NT], s_a11[NT];
    __shared__ float s_w00[NT], s_w01[NT], s_w10[NT], s_w11[NT];

    int blk = blockIdx.x;              // 2048 = B*H*(W/32)
    int wc = blk & 3, h = (blk >> 2) & (H - 1), b = blk >> 9;
    int w0 = wc * 32;
    int tid = threadIdx.x;
    int wv = tid >> 6, lane = tid & 63;
    int l16 = lane & 15, q = lane >> 4;

    // ---- phase A1: im2col of o_t into stage (9k x 32p tasks, 16 subs of 4ch) ----
    #pragma unroll 3
    for (int it = 0; it < 9; ++it) {
        int i = tid + it * 512;
        int sub = i & 15, task = i >> 4;
        int p = task & 31, k = task >> 5;
        int ky = k / 3, kx = k - ky * 3;
        int yy = h + ky - 1;
        int xx = w0 + p + kx - 1;
        ushort4 v = make_ushort4(0, 0, 0, 0);
        if ((unsigned)yy < (unsigned)H && (unsigned)xx < (unsigned)W)
            v = *reinterpret_cast<const ushort4*>(&o_t[((size_t)(b * H + yy) * W + xx) * 64 + sub * 4]);
        *reinterpret_cast<ushort4*>(&stage[p][k * 64 + sub * 4]) = v;
    }
    __syncthreads();

    // ---- phase A2: offset conv MFMA on waves 0-3; C[32ch][32px] ----
    if (wv < 4) {
        int mt = wv >> 1, pt = wv & 1;
        f32x4 acc = {0.f, 0.f, 0.f, 0.f};
        const unsigned short* arow = cmb16 + (size_t)(mt * 16 + l16) * CK;
        const unsigned short* brow = &stage[pt * 16 + l16][0];
        #pragma unroll 6
        for (int ks = 0; ks < 18; ++ks) {
            short8 a  = *reinterpret_cast<const short8*>(&arow[ks * 32 + q * 8]);
            short8 bb = *reinterpret_cast<const short8*>(&brow[ks * 32 + q * 8]);
            acc = __builtin_amdgcn_mfma_f32_16x16x32_bf16(a, bb, acc, 0, 0, 0);
        }
        #pragma unroll
        for (int r = 0; r < 4; ++r) {                   // D: col=lane&15, row=(lane>>4)*4+r
            int o = mt * 16 + q * 4 + r;
            if (o < OFF_C) {
                int p = pt * 16 + l16;
                float v = acc[r] + cmb[o];
                offs_l[o][p] = v;
                offs_out[((size_t)(b * OFF_C + o) * H + h) * W + w0 + p] = v;
            }
        }
    }
    __syncthreads();

    // ---- phase B: bilinear meta for 288 (k,p) tasks ----
    if (tid < NT) {
        int p = tid & 31, k = tid >> 5;
        int ky = k / 3, kx = k - ky * 3;
        float dyv = offs_l[2 * k][p];
        float dxv = offs_l[2 * k + 1][p];
        float py = dyv + (float)(h - 1 + ky);
        float px = dxv + (float)(w0 + p - 1 + kx);
        float fy = floorf(py), fx = floorf(px);
        int iy = (int)fy, ix = (int)fx;
        float wy = py - fy, wx = px - fx;
        bool y0 = (unsigned)iy       < (unsigned)H;
        bool y1 = (unsigned)(iy + 1) < (unsigned)H;
        bool x0 = (unsigned)ix       < (unsigned)W;
        bool x1 = (unsigned)(ix + 1) < (unsigned)W;
        int cy0 = min(max(iy, 0), H - 1),     cy1 = min(max(iy + 1, 0), H - 1);
        int cx0 = min(max(ix, 0), W - 1),     cx1 = min(max(ix + 1, 0), W - 1);
        int rb = b * H;
        s_a00[tid] = ((rb + cy0) * W + cx0) * 64;
        s_a01[tid] = ((rb + cy0) * W + cx1) * 64;
        s_a10[tid] = ((rb + cy1) * W + cx0) * 64;
        s_a11[tid] = ((rb + cy1) * W + cx1) * 64;
        s_w00[tid] = (y0 && x0) ? (1.f - wy) * (1.f - wx) : 0.f;
        s_w01[tid] = (y0 && x1) ? (1.f - wy) * wx         : 0.f;
        s_w10[tid] = (y1 && x0) ? wy * (1.f - wx)         : 0.f;
        s_w11[tid] = (y1 && x1) ? wy * wx                 : 0.f;
    }
    __syncthreads();

    // ---- phase C: gather + blend + pack into stage (samp) ----
    #pragma unroll 3
    for (int it = 0; it < 9; ++it) {
        int i = tid + it * 512;
        int sub = i & 15, task = i >> 4;
        int p = task & 31, k = task >> 5;
        int c0 = sub * 4;
        int a00 = s_a00[task], a01 = s_a01[task], a10 = s_a10[task], a11 = s_a11[task];
        float w00 = s_w00[task], w01 = s_w01[task], w10 = s_w10[task], w11 = s_w11[task];
        ushort4 v00 = *reinterpret_cast<const ushort4*>(&x_t[a00 + c0]);
        ushort4 v01 = *reinterpret_cast<const ushort4*>(&x_t[a01 + c0]);
        ushort4 v10 = *reinterpret_cast<const ushort4*>(&x_t[a10 + c0]);
        ushort4 v11 = *reinterpret_cast<const ushort4*>(&x_t[a11 + c0]);
        ushort4 o4;
        o4.x = f2bf(w00 * bf2f(v00.x) + w01 * bf2f(v01.x) + w10 * bf2f(v10.x) + w11 * bf2f(v11.x));
        o4.y = f2bf(w00 * bf2f(v00.y) + w01 * bf2f(v01.y) + w10 * bf2f(v10.y) + w11 * bf2f(v11.y));
        o4.z = f2bf(w00 * bf2f(v00.z) + w01 * bf2f(v01.z) + w10 * bf2f(v10.z) + w11 * bf2f(v11.z));
        o4.w = f2bf(w00 * bf2f(v00.w) + w01 * bf2f(v01.w) + w10 * bf2f(v10.w) + w11 * bf2f(v11.w));
        *reinterpret_cast<ushort4*>(&stage[p][k * 64 + c0]) = o4;
    }
    __syncthreads();

    // ---- phase D: main MFMA, 8 waves; C[64ch][32px] ----
    {
        int mt = wv & 3, pt = wv >> 2;
        f32x4 acc = {0.f, 0.f, 0.f, 0.f};
        const unsigned short* arow = wb16 + (size_t)(mt * 16 + l16) * CK;
        const unsigned short* brow = &stage[pt * 16 + l16][0];
        #pragma unroll 6
        for (int ks = 0; ks < 18; ++ks) {
            short8 a  = *reinterpret_cast<const short8*>(&arow[ks * 32 + q * 8]);
            short8 bb = *reinterpret_cast<const short8*>(&brow[ks * 32 + q * 8]);
            acc = __builtin_amdgcn_mfma_f32_16x16x32_bf16(a, bb, acc, 0, 0, 0);
        }
        #pragma unroll
        for (int r = 0; r < 4; ++r) {
            int o = mt * 16 + q * 4 + r;
            y_out[((size_t)(b * Cout + o) * H + h) * W + w0 + pt * 16 + l16] = acc[r] + bias[o];
        }
    }
}

// ======================= fallback fp32 path (round-1 kernels) =======================
__global__ __launch_bounds__(256)
void offset_conv_fb(const float* __restrict__ oin, const float* __restrict__ cmw,
                    const float* __restrict__ cmb, float* __restrict__ offs)
{
    int t = blockIdx.x * 256 + threadIdx.x;
    int w = t & (W - 1);
    int h = (t >> 7) & (H - 1);
    int oc = (t >> 14) % OFF_C;
    int b  = (t >> 14) / OFF_C;
    float acc = cmb[oc];
    const float* wrow  = cmw + oc * Cin * KK;
    const float* ibase = oin + b * Cin * HW;
    for (int c = 0; c < Cin; ++c) {
        const float* ip = ibase + c * HW;
        const float* wp = wrow + c * KK;
        #pragma unroll
        for (int ky = 0; ky < 3; ++ky) {
            int yy = h + ky - 1;
            if ((unsigned)yy >= (unsigned)H) continue;
            #pragma unroll
            for (int kx = 0; kx < 3; ++kx) {
                int xx = w + kx - 1;
                if ((unsigned)xx >= (unsigned)W) continue;
                acc = fmaf(ip[yy * W + xx], wp[ky * 3 + kx], acc);
            }
        }
    }
    offs[t] = acc;
}

__global__ __launch_bounds__(256)
void deform_gemm_fb(const float* __restrict__ x, const float* __restrict__ offs,
                    const float* __restrict__ wgt, const float* __restrict__ bias,
                    float* __restrict__ y)
{
    __shared__ float samp[16][580];
    __shared__ int   s_iy[144];
    __shared__ int   s_ix[144];
    __shared__ float s_wy[144];
    __shared__ float s_wx[144];
    int blk = blockIdx.x;
    int wchunk = blk & 7;
    int h = (blk >> 3) & (H - 1);
    int b = blk >> 10;
    int w0 = wchunk * 16;
    int tid = threadIdx.x;
    if (tid < 144) {
        int p = tid & 15, k = tid >> 4;
        int w = w0 + p;
        float dyv = offs[((b * OFF_C + 2 * k    ) * H + h) * W + w];
        float dxv = offs[((b * OFF_C + 2 * k + 1) * H + h) * W + w];
        float py = dyv + (float)(h - 1 + k / 3);
        float px = dxv + (float)(w - 1 + k % 3);
        float fy = floorf(py), fx = floorf(px);
        s_iy[tid] = (int)fy; s_ix[tid] = (int)fx;
        s_wy[tid] = py - fy; s_wx[tid] = px - fx;
    }
    __syncthreads();
    const float* xb = x + b * Cin * HW;
    for (int i = tid; i < Cin * KK * 16; i += 256) {
        int p = i & 15;
        int k = (i >> 4) % KK;
        int c = i / (KK * 16);
        int m = k * 16 + p;
        int iy = s_iy[m], ix = s_ix[m];
        float wy = s_wy[m], wx = s_wx[m];
        const float* xp = xb + c * HW;
        float v00 = 0.f, v01 = 0.f, v10 = 0.f, v11 = 0.f;
        bool y0ok = (unsigned)iy       < (unsigned)H;
        bool y1ok = (unsigned)(iy + 1) < (unsigned)H;
        bool x0ok = (unsigned)ix       < (unsigned)W;
        bool x1ok = (unsigned)(ix + 1) < (unsigned)W;
        if (y0ok && x0ok) v00 = xp[iy * W + ix];
        if (y0ok && x1ok) v01 = xp[iy * W + ix + 1];
        if (y1ok && x0ok) v10 = xp[(iy + 1) * W + ix];
        if (y1ok && x1ok) v11 = xp[(iy + 1) * W + ix + 1];
        samp[p][c * KK + k] = (v00 * (1.f - wx) + v01 * wx) * (1.f - wy)
                            + (v10 * (1.f - wx) + v11 * wx) * wy;
    }
    __syncthreads();
    int tp = tid & 15, to = tid >> 4;
    float acc0 = 0.f, acc1 = 0.f, acc2 = 0.f, acc3 = 0.f;
    for (int ck = 0; ck < CK; ck += 4) {
        float4 sv = *reinterpret_cast<const float4*>(&samp[tp][ck]);
        const float4 w0v = *reinterpret_cast<const float4*>(&wgt[(0 * 16 + to) * CK + ck]);
        const float4 w1v = *reinterpret_cast<const float4*>(&wgt[(1 * 16 + to) * CK + ck]);
        const float4 w2v = *reinterpret_cast<const float4*>(&wgt[(2 * 16 + to) * CK + ck]);
        const float4 w3v = *reinterpret_cast<const float4*>(&wgt[(3 * 16 + to) * CK + ck]);
        acc0 = fmaf(sv.x, w0v.x, acc0); acc0 = fmaf(sv.y, w0v.y, acc0);
        acc0 = fmaf(sv.z, w0v.z, acc0); acc0 = fmaf(sv.w, w0v.w, acc0);
        acc1 = fmaf(sv.x, w1v.x, acc1); acc1 = fmaf(sv.y, w1v.y, acc1);
        acc1 = fmaf(sv.z, w1v.z, acc1); acc1 = fmaf(sv.w, w1v.w, acc1);
        acc2 = fmaf(sv.x, w2v.x, acc2); acc2 = fmaf(sv.y, w2v.y, acc2);
        acc2 = fmaf(sv.z, w2v.z, acc2); acc2 = fmaf(sv.w, w2v.w, acc2);
        acc3 = fmaf(sv.x, w3v.x, acc3); acc3 = fmaf(sv.y, w3v.y, acc3);
        acc3 = fmaf(sv.z, w3v.z, acc3); acc3 = fmaf(sv.w, w3v.w, acc3);
    }
    int wcol = w0 + tp;
    y[((b * Cout + (0 * 16 + to)) * H + h) * W + wcol] = acc0 + bias[0 * 16 + to];
    y[((b * Cout + (1 * 16 + to)) * H + h) * W + wcol] = acc1 + bias[1 * 16 + to];
    y[((b * Cout + (2 * 16 + to)) * H + h) * W + wcol] = acc2 + bias[2 * 16 + to];
    y[((b * Cout + (3 * 16 + to)) * H + h) * W + wcol] = acc3 + bias[3 * 16 + to];
}

extern "C" void kernel_launch(void* const* d_in, const int* in_sizes, int n_in,
                              void* d_out, int out_size, void* d_ws, size_t ws_size,
                              hipStream_t stream) {
    const float* x         = (const float*)d_in[0];
    const float* offset_in = (const float*)d_in[1];
    const float* weight    = (const float*)d_in[2];
    const float* bias      = (const float*)d_in[3];
    const float* cm_w      = (const float*)d_in[4];
    const float* cm_b      = (const float*)d_in[5];

    float* out  = (float*)d_out;
    float* offs = out;                    // output 0: (B,18,H,W)
    float* yout = out + OFFSET_ELEMS;     // output 1: (B,64,H,W)

    if (ws_size >= WS_NEEDED) {
        unsigned short* x_t   = (unsigned short*)((char*)d_ws + XT_OFF);
        unsigned short* o_t   = (unsigned short*)((char*)d_ws + OT_OFF);
        unsigned short* wb16  = (unsigned short*)((char*)d_ws + WB_OFF);
        unsigned short* cmb16 = (unsigned short*)((char*)d_ws + CMB_OFF);

        prep_all<<<2048 + 64, 256, 0, stream>>>(x, offset_in, weight, cm_w,
                                                x_t, o_t, wb16, cmb16);
        dcn_fused<<<B * H * (W / PIX), 512, 0, stream>>>(x_t, o_t, wb16, cmb16,
                                                         cm_b, bias, offs, yout);
    } else {
        offset_conv_fb<<<OFFSET_ELEMS / 256, 256, 0, stream>>>(offset_in, cm_w, cm_b, offs);
        deform_gemm_fb<<<B * H * (W / 16), 256, 0, stream>>>(x, offs, weight, bias, yout);
    }
}

// Round 4
// 78.192 us; speedup vs baseline: 7.4261x; 1.1386x over previous
//
#include <hip/hip_runtime.h>

// DCNv2 forward: B=4, Cin=64, Cout=64, K=3, H=W=128, S=1, P=1
constexpr int B    = 4;
constexpr int Cin  = 64;
constexpr int Cout = 64;
constexpr int H    = 128;
constexpr int W    = 128;
constexpr int KK   = 9;
constexpr int HW   = H * W;
constexpr int OFF_C = 18;                       // mask channels unused by reference
constexpr int OFFSET_ELEMS = B * OFF_C * HW;
constexpr int CK   = Cin * KK;                  // 576
constexpr int SAMP_STRIDE = CK + 8;             // 584 ushorts = 1168B (16B-aligned)
constexpr int PIX  = 32;                        // pixels per fused block
constexpr int NT8  = KK * PIX * 8;              // 2304 thread-tasks (8 subs of 8ch)

typedef __attribute__((ext_vector_type(8))) short          short8;
typedef __attribute__((ext_vector_type(8))) unsigned short ushort8;
typedef __attribute__((ext_vector_type(4))) float          f32x4;

// ---- workspace layout (bf16 NHWC tensors + reordered bf16 weights) ----
constexpr size_t XT_OFF  = 0;                               // x_t[B][H][W][64] bf16
constexpr size_t XT_SZ   = (size_t)B * HW * 64 * 2;
constexpr size_t OT_OFF  = XT_OFF + XT_SZ;                  // o_t NHWC bf16
constexpr size_t OT_SZ   = XT_SZ;
constexpr size_t WB_OFF  = OT_OFF + OT_SZ;                  // wb16[64][576], ck' = k*64+c
constexpr size_t WB_SZ   = (size_t)64 * CK * 2;
constexpr size_t CMB_OFF = WB_OFF + WB_SZ;                  // cmb16[32][576], rows>=18 zero
constexpr size_t CMB_SZ  = (size_t)32 * CK * 2;
constexpr size_t WS_NEEDED = CMB_OFF + CMB_SZ;

__device__ __forceinline__ unsigned short f2bf(float f) {   // round-to-nearest-even
    unsigned u = __builtin_bit_cast(unsigned, f);
    u += 0x7FFFu + ((u >> 16) & 1u);
    return (unsigned short)(u >> 16);
}
__device__ __forceinline__ float bf2f(unsigned short h) {
    unsigned u = (unsigned)h << 16;
    return __builtin_bit_cast(float, u);
}

// ============ prep: NCHW fp32 -> NHWC bf16 (x, offset_in) + weight reorder ============
__global__ __launch_bounds__(256)
void prep_all(const float* __restrict__ x, const float* __restrict__ oin,
              const float* __restrict__ wgt, const float* __restrict__ cmw,
              unsigned short* __restrict__ x_t, unsigned short* __restrict__ o_t,
              unsigned short* __restrict__ wb16, unsigned short* __restrict__ cmb16)
{
    __shared__ float tile[64][68];
    int idx = blockIdx.x;
    int t = threadIdx.x;
    if (idx < 2048) {                 // transpose: bit10 = tensor, bits 8-9 = b, 1-7 = h, 0 = wtile
        int tensor = idx >> 10;
        int blk = idx & 1023;
        int wt = blk & 1, h = (blk >> 1) & (H - 1), b = blk >> 8;
        const float* src = (tensor ? oin : x) + (size_t)b * Cin * HW + h * W + wt * 64;
        unsigned short* dst = (tensor ? o_t : x_t) + ((size_t)(b * H + h) * W + wt * 64) * 64;
        int lane16 = t & 15, grp = t >> 4;
        #pragma unroll
        for (int i = 0; i < 4; ++i) {
            int c = grp + 16 * i;
            float4 v = *reinterpret_cast<const float4*>(&src[c * HW + lane16 * 4]);
            int w0 = lane16 * 4;
            tile[w0 + 0][c] = v.x; tile[w0 + 1][c] = v.y;
            tile[w0 + 2][c] = v.z; tile[w0 + 3][c] = v.w;
        }
        __syncthreads();
        #pragma unroll
        for (int i = 0; i < 4; ++i) {
            int w = grp + 16 * i;
            const float* tr = &tile[w][lane16 * 4];
            ushort4 o4;
            o4.x = f2bf(tr[0]); o4.y = f2bf(tr[1]); o4.z = f2bf(tr[2]); o4.w = f2bf(tr[3]);
            *reinterpret_cast<ushort4*>(&dst[(size_t)w * 64 + lane16 * 4]) = o4;
        }
    } else {                          // weight prep: 64 blocks
        int i0 = (idx - 2048) * 256 + t;
        int stride = 64 * 256;
        for (int i = i0; i < 64 * CK; i += stride) {
            int o = i / CK, ckp = i - o * CK;
            int k = ckp >> 6, c = ckp & 63;
            wb16[i] = f2bf(wgt[(o * 64 + c) * 9 + k]);
        }
        for (int i = i0; i < 32 * CK; i += stride) {
            int o = i / CK, ckp = i - o * CK;
            int k = ckp >> 6, c = ckp & 63;
            cmb16[i] = (o < OFF_C) ? f2bf(cmw[(o * 64 + c) * 9 + k]) : (unsigned short)0;
        }
    }
}

// ============ fused: offset-conv MFMA -> bilinear sample -> main MFMA ============
__global__ __launch_bounds__(512, 8)
void dcn_fused(const unsigned short* __restrict__ x_t,
               const unsigned short* __restrict__ o_t,
               const unsigned short* __restrict__ wb16,
               const unsigned short* __restrict__ cmb16,
               const float* __restrict__ cmb,     // (27,)
               const float* __restrict__ bias,    // (64,)
               float* __restrict__ offs_out,      // (B,18,H,W)
               float* __restrict__ y_out)         // (B,64,H,W)
{
    __shared__ unsigned short stage[PIX][SAMP_STRIDE];   // 37,376 B: o_t patch, then samp
    __shared__ float offs_l[OFF_C][PIX];                 // 2,304 B -> total 39,680 B

    // XCD-chunked swizzle: 2048 blocks, 8 XCDs -> each XCD owns a contiguous
    // 256-block chunk (= half of one batch image) so x_t slice (~1MB) L2-fits.
    int bid = blockIdx.x;
    int blk = (bid & 7) * 256 + (bid >> 3);

    int wc = blk & 3, h = (blk >> 2) & (H - 1), b = blk >> 9;
    int w0 = wc * 32;
    int tid = threadIdx.x;
    int wv = tid >> 6, lane = tid & 63;
    int l16 = lane & 15, q = lane >> 4;

    // ---- phase A1: im2col of o_t into stage (288 tasks x 8 subs of 8ch) ----
    {
        auto bodyA = [&](int i) {
            int sub = i & 7, task = i >> 3;
            int p = task & 31, k = task >> 5;
            int ky = k / 3, kx = k - ky * 3;
            int yy = h + ky - 1;
            int xx = w0 + p + kx - 1;
            ushort8 v = {0, 0, 0, 0, 0, 0, 0, 0};
            if ((unsigned)yy < (unsigned)H && (unsigned)xx < (unsigned)W)
                v = *reinterpret_cast<const ushort8*>(&o_t[((size_t)(b * H + yy) * W + xx) * 64 + sub * 8]);
            *reinterpret_cast<ushort8*>(&stage[p][k * 64 + sub * 8]) = v;
        };
        #pragma unroll 1
        for (int it = 0; it < 4; ++it) bodyA(tid + it * 512);
        if (tid < NT8 - 2048) bodyA(tid + 2048);
    }
    __syncthreads();

    // ---- phase A2: offset conv MFMA on waves 0-3; C[32ch][32px] ----
    if (wv < 4) {
        int mt = wv >> 1, pt = wv & 1;
        f32x4 acc = {0.f, 0.f, 0.f, 0.f};
        const unsigned short* arow = cmb16 + (size_t)(mt * 16 + l16) * CK;
        const unsigned short* brow = &stage[pt * 16 + l16][0];
        #pragma unroll 6
        for (int ks = 0; ks < 18; ++ks) {
            short8 a  = *reinterpret_cast<const short8*>(&arow[ks * 32 + q * 8]);
            short8 bb = *reinterpret_cast<const short8*>(&brow[ks * 32 + q * 8]);
            acc = __builtin_amdgcn_mfma_f32_16x16x32_bf16(a, bb, acc, 0, 0, 0);
        }
        #pragma unroll
        for (int r = 0; r < 4; ++r) {                   // D: col=lane&15, row=(lane>>4)*4+r
            int o = mt * 16 + q * 4 + r;
            if (o < OFF_C) {
                int p = pt * 16 + l16;
                float v = acc[r] + cmb[o];
                offs_l[o][p] = v;
                offs_out[((size_t)(b * OFF_C + o) * H + h) * W + w0 + p] = v;
            }
        }
    }
    __syncthreads();

    // ---- phase C: inline meta + gather + blend + pack into stage (samp) ----
    {
        auto bodyC = [&](int i) {
            int sub = i & 7, task = i >> 3;
            int p = task & 31, k = task >> 5;
            int ky = k / 3, kx = k - ky * 3;
            int c0 = sub * 8;
            float dyv = offs_l[2 * k][p];
            float dxv = offs_l[2 * k + 1][p];
            float py = dyv + (float)(h - 1 + ky);
            float px = dxv + (float)(w0 + p - 1 + kx);
            float fy = floorf(py), fx = floorf(px);
            int iy = (int)fy, ix = (int)fx;
            float wy = py - fy, wx = px - fx;
            bool y0 = (unsigned)iy       < (unsigned)H;
            bool y1 = (unsigned)(iy + 1) < (unsigned)H;
            bool x0 = (unsigned)ix       < (unsigned)W;
            bool x1 = (unsigned)(ix + 1) < (unsigned)W;
            int cy0 = min(max(iy, 0), H - 1),     cy1 = min(max(iy + 1, 0), H - 1);
            int cx0 = min(max(ix, 0), W - 1),     cx1 = min(max(ix + 1, 0), W - 1);
            int rb = b * H;
            int a00 = ((rb + cy0) * W + cx0) * 64 + c0;
            int a01 = ((rb + cy0) * W + cx1) * 64 + c0;
            int a10 = ((rb + cy1) * W + cx0) * 64 + c0;
            int a11 = ((rb + cy1) * W + cx1) * 64 + c0;
            float w00 = (y0 && x0) ? (1.f - wy) * (1.f - wx) : 0.f;
            float w01 = (y0 && x1) ? (1.f - wy) * wx         : 0.f;
            float w10 = (y1 && x0) ? wy * (1.f - wx)         : 0.f;
            float w11 = (y1 && x1) ? wy * wx                 : 0.f;
            ushort8 v00 = *reinterpret_cast<const ushort8*>(&x_t[a00]);
            ushort8 v01 = *reinterpret_cast<const ushort8*>(&x_t[a01]);
            ushort8 v10 = *reinterpret_cast<const ushort8*>(&x_t[a10]);
            ushort8 v11 = *reinterpret_cast<const ushort8*>(&x_t[a11]);
            ushort8 o8;
            #pragma unroll
            for (int j = 0; j < 8; ++j) {
                float v = w00 * bf2f((unsigned short)v00[j]) + w01 * bf2f((unsigned short)v01[j])
                        + w10 * bf2f((unsigned short)v10[j]) + w11 * bf2f((unsigned short)v11[j]);
                o8[j] = (short)f2bf(v);
            }
            *reinterpret_cast<ushort8*>(&stage[p][k * 64 + c0]) = o8;
        };
        #pragma unroll 1
        for (int it = 0; it < 4; ++it) bodyC(tid + it * 512);
        if (tid < NT8 - 2048) bodyC(tid + 2048);
    }
    __syncthreads();

    // ---- phase D: main MFMA, 8 waves; C[64ch][32px] ----
    {
        int mt = wv & 3, pt = wv >> 2;
        f32x4 acc = {0.f, 0.f, 0.f, 0.f};
        const unsigned short* arow = wb16 + (size_t)(mt * 16 + l16) * CK;
        const unsigned short* brow = &stage[pt * 16 + l16][0];
        #pragma unroll 6
        for (int ks = 0; ks < 18; ++ks) {
            short8 a  = *reinterpret_cast<const short8*>(&arow[ks * 32 + q * 8]);
            short8 bb = *reinterpret_cast<const short8*>(&brow[ks * 32 + q * 8]);
            acc = __builtin_amdgcn_mfma_f32_16x16x32_bf16(a, bb, acc, 0, 0, 0);
        }
        #pragma unroll
        for (int r = 0; r < 4; ++r) {
            int o = mt * 16 + q * 4 + r;
            y_out[((size_t)(b * Cout + o) * H + h) * W + w0 + pt * 16 + l16] = acc[r] + bias[o];
        }
    }
}

// ======================= fallback fp32 path (round-1 kernels) =======================
__global__ __launch_bounds__(256)
void offset_conv_fb(const float* __restrict__ oin, const float* __restrict__ cmw,
                    const float* __restrict__ cmb, float* __restrict__ offs)
{
    int t = blockIdx.x * 256 + threadIdx.x;
    int w = t & (W - 1);
    int h = (t >> 7) & (H - 1);
    int oc = (t >> 14) % OFF_C;
    int b  = (t >> 14) / OFF_C;
    float acc = cmb[oc];
    const float* wrow  = cmw + oc * Cin * KK;
    const float* ibase = oin + b * Cin * HW;
    for (int c = 0; c < Cin; ++c) {
        const float* ip = ibase + c * HW;
        const float* wp = wrow + c * KK;
        #pragma unroll
        for (int ky = 0; ky < 3; ++ky) {
            int yy = h + ky - 1;
            if ((unsigned)yy >= (unsigned)H) continue;
            #pragma unroll
            for (int kx = 0; kx < 3; ++kx) {
                int xx = w + kx - 1;
                if ((unsigned)xx >= (unsigned)W) continue;
                acc = fmaf(ip[yy * W + xx], wp[ky * 3 + kx], acc);
            }
        }
    }
    offs[t] = acc;
}

__global__ __launch_bounds__(256)
void deform_gemm_fb(const float* __restrict__ x, const float* __restrict__ offs,
                    const float* __restrict__ wgt, const float* __restrict__ bias,
                    float* __restrict__ y)
{
    __shared__ float samp[16][580];
    __shared__ int   s_iy[144];
    __shared__ int   s_ix[144];
    __shared__ float s_wy[144];
    __shared__ float s_wx[144];
    int blk = blockIdx.x;
    int wchunk = blk & 7;
    int h = (blk >> 3) & (H - 1);
    int b = blk >> 10;
    int w0 = wchunk * 16;
    int tid = threadIdx.x;
    if (tid < 144) {
        int p = tid & 15, k = tid >> 4;
        int w = w0 + p;
        float dyv = offs[((b * OFF_C + 2 * k    ) * H + h) * W + w];
        float dxv = offs[((b * OFF_C + 2 * k + 1) * H + h) * W + w];
        float py = dyv + (float)(h - 1 + k / 3);
        float px = dxv + (float)(w - 1 + k % 3);
        float fy = floorf(py), fx = floorf(px);
        s_iy[tid] = (int)fy; s_ix[tid] = (int)fx;
        s_wy[tid] = py - fy; s_wx[tid] = px - fx;
    }
    __syncthreads();
    const float* xb = x + b * Cin * HW;
    for (int i = tid; i < Cin * KK * 16; i += 256) {
        int p = i & 15;
        int k = (i >> 4) % KK;
        int c = i / (KK * 16);
        int m = k * 16 + p;
        int iy = s_iy[m], ix = s_ix[m];
        float wy = s_wy[m], wx = s_wx[m];
        const float* xp = xb + c * HW;
        float v00 = 0.f, v01 = 0.f, v10 = 0.f, v11 = 0.f;
        bool y0ok = (unsigned)iy       < (unsigned)H;
        bool y1ok = (unsigned)(iy + 1) < (unsigned)H;
        bool x0ok = (unsigned)ix       < (unsigned)W;
        bool x1ok = (unsigned)(ix + 1) < (unsigned)W;
        if (y0ok && x0ok) v00 = xp[iy * W + ix];
        if (y0ok && x1ok) v01 = xp[iy * W + ix + 1];
        if (y1ok && x0ok) v10 = xp[(iy + 1) * W + ix];
        if (y1ok && x1ok) v11 = xp[(iy + 1) * W + ix + 1];
        samp[p][c * KK + k] = (v00 * (1.f - wx) + v01 * wx) * (1.f - wy)
                            + (v10 * (1.f - wx) + v11 * wx) * wy;
    }
    __syncthreads();
    int tp = tid & 15, to = tid >> 4;
    float acc0 = 0.f, acc1 = 0.f, acc2 = 0.f, acc3 = 0.f;
    for (int ck = 0; ck < CK; ck += 4) {
        float4 sv = *reinterpret_cast<const float4*>(&samp[tp][ck]);
        const float4 w0v = *reinterpret_cast<const float4*>(&wgt[(0 * 16 + to) * CK + ck]);
        const float4 w1v = *reinterpret_cast<const float4*>(&wgt[(1 * 16 + to) * CK + ck]);
        const float4 w2v = *reinterpret_cast<const float4*>(&wgt[(2 * 16 + to) * CK + ck]);
        const float4 w3v = *reinterpret_cast<const float4*>(&wgt[(3 * 16 + to) * CK + ck]);
        acc0 = fmaf(sv.x, w0v.x, acc0); acc0 = fmaf(sv.y, w0v.y, acc0);
        acc0 = fmaf(sv.z, w0v.z, acc0); acc0 = fmaf(sv.w, w0v.w, acc0);
        acc1 = fmaf(sv.x, w1v.x, acc1); acc1 = fmaf(sv.y, w1v.y, acc1);
        acc1 = fmaf(sv.z, w1v.z, acc1); acc1 = fmaf(sv.w, w1v.w, acc1);
        acc2 = fmaf(sv.x, w2v.x, acc2); acc2 = fmaf(sv.y, w2v.y, acc2);
        acc2 = fmaf(sv.z, w2v.z, acc2); acc2 = fmaf(sv.w, w2v.w, acc2);
        acc3 = fmaf(sv.x, w3v.x, acc3); acc3 = fmaf(sv.y, w3v.y, acc3);
        acc3 = fmaf(sv.z, w3v.z, acc3); acc3 = fmaf(sv.w, w3v.w, acc3);
    }
    int wcol = w0 + tp;
    y[((b * Cout + (0 * 16 + to)) * H + h) * W + wcol] = acc0 + bias[0 * 16 + to];
    y[((b * Cout + (1 * 16 + to)) * H + h) * W + wcol] = acc1 + bias[1 * 16 + to];
    y[((b * Cout + (2 * 16 + to)) * H + h) * W + wcol] = acc2 + bias[2 * 16 + to];
    y[((b * Cout + (3 * 16 + to)) * H + h) * W + wcol] = acc3 + bias[3 * 16 + to];
}

extern "C" void kernel_launch(void* const* d_in, const int* in_sizes, int n_in,
                              void* d_out, int out_size, void* d_ws, size_t ws_size,
                              hipStream_t stream) {
    const float* x         = (const float*)d_in[0];
    const float* offset_in = (const float*)d_in[1];
    const float* weight    = (const float*)d_in[2];
    const float* bias      = (const float*)d_in[3];
    const float* cm_w      = (const float*)d_in[4];
    const float* cm_b      = (const float*)d_in[5];

    float* out  = (float*)d_out;
    float* offs = out;                    // output 0: (B,18,H,W)
    float* yout = out + OFFSET_ELEMS;     // output 1: (B,64,H,W)

    if (ws_size >= WS_NEEDED) {
        unsigned short* x_t   = (unsigned short*)((char*)d_ws + XT_OFF);
        unsigned short* o_t   = (unsigned short*)((char*)d_ws + OT_OFF);
        unsigned short* wb16  = (unsigned short*)((char*)d_ws + WB_OFF);
        unsigned short* cmb16 = (unsigned short*)((char*)d_ws + CMB_OFF);

        prep_all<<<2048 + 64, 256, 0, stream>>>(x, offset_in, weight, cm_w,
                                                x_t, o_t, wb16, cmb16);
        dcn_fused<<<B * H * (W / PIX), 512, 0, stream>>>(x_t, o_t, wb16, cmb16,
                                                         cm_b, bias, offs, yout);
    } else {
        offset_conv_fb<<<OFFSET_ELEMS / 256, 256, 0, stream>>>(offset_in, cm_w, cm_b, offs);
        deform_gemm_fb<<<B * H * (W / 16), 256, 0, stream>>>(x, offs, weight, bias, yout);
    }
}